// Round 2
// baseline (57.627 us; speedup 1.0000x reference)
//
#include <hip/hip_runtime.h>

#define LN_EPS 1e-5f

// out[b,n,f,e] = LN(x[b,n,:])[f] * w[f,e] + (pb[f,e] + emb[f,e])
// B=4, N=4096, F=64, E=64 -> rows = 16384, 4096 fp32 outputs per row.
//
// Persistent-block design: 2048 blocks x 256 threads, each block grid-strides
// 8 rows. Per-thread w / (pb+emb) fragments live in registers across all rows
// (no per-row table traffic). LayerNorm is computed redundantly per wave via
// 64-lane butterfly (F==wave width), xn distributed by __shfl — no LDS, no
// __syncthreads. Next row's x load is prefetched under current row's stores.

__global__ __launch_bounds__(256) void pte_kernel(
    const float* __restrict__ x,      // [rows, 64]
    const float* __restrict__ gamma,  // [64]
    const float* __restrict__ beta,   // [64]
    const float* __restrict__ w,      // [64, 64]
    const float* __restrict__ pb,     // [64, 64]
    const float* __restrict__ emb,    // [64, 64]
    float* __restrict__ out,          // [rows, 4096]
    int rows)
{
    const int tid  = threadIdx.x;
    const int lane = tid & 63;
    const int wave = tid >> 6;

    // --- Load per-thread table fragments once (16 float4 indices / thread) ---
    const float4* __restrict__ w4 = (const float4*)w;
    const float4* __restrict__ b4 = (const float4*)pb;
    const float4* __restrict__ e4 = (const float4*)emb;

    float4 wv[4], cv[4];
    #pragma unroll
    for (int i = 0; i < 4; ++i) {
        int idx = i * 256 + tid;      // float4 index in [0,1024)
        wv[i] = w4[idx];
        float4 bv = b4[idx], ev = e4[idx];
        cv[i].x = bv.x + ev.x;
        cv[i].y = bv.y + ev.y;
        cv[i].z = bv.z + ev.z;
        cv[i].w = bv.w + ev.w;
    }
    const float g  = gamma[lane];
    const float bt = beta[lane];

    // Source lane for this thread's xn broadcast, per i:
    // f = (i*256 + tid) >> 4 = i*16 + wave*4 + (lane>>4)
    const int fbase = wave * 4 + (lane >> 4);

    int row = blockIdx.x;
    float v = (row < rows) ? x[(size_t)row * 64 + lane] : 0.0f;

    for (; row < rows; row += gridDim.x) {
        // --- LayerNorm (wave-redundant, butterfly over 64 lanes) ---
        float s = v;
        #pragma unroll
        for (int m = 1; m < 64; m <<= 1) s += __shfl_xor(s, m, 64);
        float mu = s * (1.0f / 64.0f);
        float d  = v - mu;
        float s2 = d * d;
        #pragma unroll
        for (int m = 1; m < 64; m <<= 1) s2 += __shfl_xor(s2, m, 64);
        float inv = rsqrtf(s2 * (1.0f / 64.0f) + LN_EPS);
        float xn_lane = d * inv * g + bt;

        // --- Prefetch next row's x under the stores ---
        int nrow = row + gridDim.x;
        float vn = (nrow < rows) ? x[(size_t)nrow * 64 + lane] : 0.0f;

        // --- Emit 4096 floats as 1024 float4 stores (4 / thread) ---
        float4* __restrict__ o4 = (float4*)(out + (size_t)row * 4096);
        #pragma unroll
        for (int i = 0; i < 4; ++i) {
            float xn = __shfl(xn_lane, i * 16 + fbase, 64);
            float4 r;
            r.x = fmaf(xn, wv[i].x, cv[i].x);
            r.y = fmaf(xn, wv[i].y, cv[i].y);
            r.z = fmaf(xn, wv[i].z, cv[i].z);
            r.w = fmaf(xn, wv[i].w, cv[i].w);
            o4[i * 256 + tid] = r;
        }
        v = vn;
    }
}

extern "C" void kernel_launch(void* const* d_in, const int* in_sizes, int n_in,
                              void* d_out, int out_size, void* d_ws, size_t ws_size,
                              hipStream_t stream) {
    const float* x     = (const float*)d_in[0];  // [4,4096,64]
    const float* gamma = (const float*)d_in[1];  // [64]
    const float* beta  = (const float*)d_in[2];  // [64]
    const float* w     = (const float*)d_in[3];  // [64,64]
    const float* pb    = (const float*)d_in[4];  // [64,64]
    const float* emb   = (const float*)d_in[5];  // [64,64]
    float* out = (float*)d_out;

    const int rows = 4 * 4096;   // B * N
    const int grid = 2048;       // 8 blocks/CU * 256 CUs, persistent
    pte_kernel<<<grid, 256, 0, stream>>>(x, gamma, beta, w, pb, emb, out, rows);
}

// Round 4
// 51.051 us; speedup vs baseline: 1.1288x; 1.1288x over previous
//
#include <hip/hip_runtime.h>

#define LN_EPS 1e-5f

// out[b,n,f,e] = LN(x[b,n,:])[f] * w[f,e] + (pb[f,e] + emb[f,e])
// B=4, N=4096, F=64, E=64 -> rows = 16384, 4096 fp32 outputs per row.
//
// R3 = R2 with native ext_vector_type float4 so __builtin_nontemporal_store
// compiles (HIP_vector_type is a struct and is rejected).
//  - no LDS / no __syncthreads: each wave computes LN redundantly (x row is a
//    256 B L1 hit for waves 1-3) and xn is distributed in-wave via __shfl.
//  - joint sum/sumsq butterfly: 6 dependent cross-lane steps instead of 12.
//  - nontemporal float4 stores: output is write-once; keep it from thrashing
//    the per-XCD L2 so the 48 KiB tables stay L2-resident.

typedef float f4 __attribute__((ext_vector_type(4)));

__global__ __launch_bounds__(256) void pte_kernel(
    const float* __restrict__ x,      // [rows, 64]
    const float* __restrict__ gamma,  // [64]
    const float* __restrict__ beta,   // [64]
    const float* __restrict__ w,      // [64, 64]
    const float* __restrict__ pb,     // [64, 64]
    const float* __restrict__ emb,    // [64, 64]
    float* __restrict__ out)          // [rows, 4096]
{
    const int row  = blockIdx.x;
    const int tid  = threadIdx.x;
    const int lane = tid & 63;

    // --- Issue table loads first (independent of LN) ---
    const f4* __restrict__ w4 = (const f4*)w;
    const f4* __restrict__ b4 = (const f4*)pb;
    const f4* __restrict__ e4 = (const f4*)emb;

    f4 wv[4], bv[4], ev[4];
    #pragma unroll
    for (int i = 0; i < 4; ++i) {
        int idx = i * 256 + tid;      // float4 index in [0,1024)
        wv[i] = w4[idx];
        bv[i] = b4[idx];
        ev[i] = e4[idx];
    }

    // --- LayerNorm (wave-redundant, joint sum/sumsq butterfly) ---
    float v  = x[(size_t)row * 64 + lane];
    float g  = gamma[lane];
    float bt = beta[lane];

    float s  = v;
    float s2 = v * v;
    #pragma unroll
    for (int m = 1; m < 64; m <<= 1) {
        s  += __shfl_xor(s,  m, 64);
        s2 += __shfl_xor(s2, m, 64);
    }
    float mu  = s * (1.0f / 64.0f);
    float var = fmaf(-mu, mu, s2 * (1.0f / 64.0f));
    float inv = rsqrtf(var + LN_EPS);
    float xn_lane = (v - mu) * inv * g + bt;

    // f for this thread's i-th chunk: f = i*16 + (tid>>4); as a lane index
    // within this wave: i*16 + wave*4 + (lane>>4) == i*16 + fbase.
    const int fbase = ((tid >> 6) << 2) + (lane >> 4);

    // --- Emit 4096 floats as 1024 nontemporal float4 stores (4 / thread) ---
    f4* __restrict__ o4 = (f4*)(out + (size_t)row * 4096);
    #pragma unroll
    for (int i = 0; i < 4; ++i) {
        float xn = __shfl(xn_lane, i * 16 + fbase, 64);
        f4 r;
        r.x = fmaf(xn, wv[i].x, bv[i].x + ev[i].x);
        r.y = fmaf(xn, wv[i].y, bv[i].y + ev[i].y);
        r.z = fmaf(xn, wv[i].z, bv[i].z + ev[i].z);
        r.w = fmaf(xn, wv[i].w, bv[i].w + ev[i].w);
        __builtin_nontemporal_store(r, &o4[i * 256 + tid]);
    }
}

extern "C" void kernel_launch(void* const* d_in, const int* in_sizes, int n_in,
                              void* d_out, int out_size, void* d_ws, size_t ws_size,
                              hipStream_t stream) {
    const float* x     = (const float*)d_in[0];  // [4,4096,64]
    const float* gamma = (const float*)d_in[1];  // [64]
    const float* beta  = (const float*)d_in[2];  // [64]
    const float* w     = (const float*)d_in[3];  // [64,64]
    const float* pb    = (const float*)d_in[4];  // [64,64]
    const float* emb   = (const float*)d_in[5];  // [64,64]
    float* out = (float*)d_out;

    const int rows = 4 * 4096;  // B * N
    pte_kernel<<<rows, 256, 0, stream>>>(x, gamma, beta, w, pb, emb, out);
}